// Round 4
// baseline (2763.461 us; speedup 1.0000x reference)
//
#include <hip/hip_runtime.h>

// ---------------------------------------------------------------------------
// LSTM autoencoder w/ attention, MI355X fp16-MFMA implementation.
// S=128, B=256, IN=H=OUT=1024.  All GEMMs plain fp16 inputs, fp32 accumulate.
// R5: fixes R4's k_step data race.  R4 mixed register global loads and
//     global_load_lds in one vmcnt region without ordering fences; the
//     scheduler reorders them, invalidating the counted vmcnt -> stale B
//     tiles.  Now: every VMEM group is pinned with asm ""::: "memory"
//     fences, loadA/stage issue at END of the iter body (after ds_reads),
//     and the counted waits use guaranteed-younger-op counts only
//     (4,6,8-steady,6,2).  Buffer overwrite is again separated from its
//     readers by a full barrier interval (R3 discipline).
// ---------------------------------------------------------------------------

typedef _Float16 half8 __attribute__((ext_vector_type(8)));
typedef float f32x4 __attribute__((ext_vector_type(4)));
typedef float f32x16 __attribute__((ext_vector_type(16)));

#define S_  128
#define B_  256
#define HDIM 1024
#define BH  262144          // B*H

// async global -> LDS, 16B per lane, wave-uniform LDS base
__device__ __forceinline__ void g2l16(void* lds_base, const void* g) {
  __builtin_amdgcn_global_load_lds(
      (const __attribute__((address_space(1))) void*)g,
      (__attribute__((address_space(3))) void*)lds_base, 16, 0, 0);
}

__device__ __forceinline__ float sigmoidf_(float x) {
  return 1.f / (1.f + __expf(-x));
}
__device__ __forceinline__ float tanhf_(float x) {
  float e = __expf(-2.f * fabsf(x));
  float t = (1.f - e) / (1.f + e);
  return x < 0.f ? -t : t;
}

// --------------------------- converters ------------------------------------
__global__ __launch_bounds__(256) void k_cvt(const float* __restrict__ src,
                                             _Float16* __restrict__ dst) {
  size_t i = ((size_t)blockIdx.x * 256 + threadIdx.x) * 8;
  float4 u = *(const float4*)(src + i);
  float4 v = *(const float4*)(src + i + 4);
  half8 h;
  h[0] = u.x; h[1] = u.y; h[2] = u.z; h[3] = u.w;
  h[4] = v.x; h[5] = v.y; h[6] = v.z; h[7] = v.w;
  *(half8*)(dst + i) = h;
}

// Wcat[r][k] = k<1024 ? W_ih[r][k] : W_hh[r][k-1024]   (fp16, [4096][2048])
__global__ __launch_bounds__(256) void k_wcat(const float* __restrict__ Wih,
                                              const float* __restrict__ Whh,
                                              _Float16* __restrict__ Wc) {
  size_t i = ((size_t)blockIdx.x * 256 + threadIdx.x) * 8;
  int r = (int)(i >> 11), k = (int)(i & 2047);
  const float* src = (k < 1024) ? (Wih + (size_t)r * 1024 + k)
                                : (Whh + (size_t)r * 1024 + (k - 1024));
  float4 u = *(const float4*)(src);
  float4 v = *(const float4*)(src + 4);
  half8 h;
  h[0] = u.x; h[1] = u.y; h[2] = u.z; h[3] = u.w;
  h[4] = v.x; h[5] = v.y; h[6] = v.z; h[7] = v.w;
  *(half8*)(Wc + i) = h;
}

// cbuf = c0 ; hs[0] = fp16(h0) ; bias = b_ih + b_hh
__global__ __launch_bounds__(256) void k_init(const float* __restrict__ h0,
                                              const float* __restrict__ c0,
                                              const float* __restrict__ bih,
                                              const float* __restrict__ bhh,
                                              _Float16* __restrict__ hs0,
                                              float* __restrict__ cbuf,
                                              float* __restrict__ bias) {
  int i = blockIdx.x * 256 + threadIdx.x;   // 262144 total
  cbuf[i] = c0[i];
  hs0[i] = (_Float16)h0[i];
  if (i < 4096) bias[i] = bih[i] + bhh[i];
}

// row softmax of attnW [128][128] -> fp16 Ah + fp16 residual Ar
__global__ __launch_bounds__(64) void k_softmax(const float* __restrict__ W,
                                                _Float16* __restrict__ Ah,
                                                _Float16* __restrict__ Ar) {
  int r = blockIdx.x, lane = threadIdx.x;
  float v0 = W[r * 128 + lane], v1 = W[r * 128 + 64 + lane];
  float m = fmaxf(v0, v1);
  for (int off = 32; off; off >>= 1) m = fmaxf(m, __shfl_xor(m, off));
  float e0 = __expf(v0 - m), e1 = __expf(v1 - m);
  float s = e0 + e1;
  for (int off = 32; off; off >>= 1) s += __shfl_xor(s, off);
  float inv = 1.f / s;
  float a0 = e0 * inv, a1 = e1 * inv;
  _Float16 h0 = (_Float16)a0, h1 = (_Float16)a1;
  Ah[r * 128 + lane] = h0;
  Ah[r * 128 + 64 + lane] = h1;
  Ar[r * 128 + lane] = (_Float16)(a0 - (float)h0);
  Ar[r * 128 + 64 + lane] = (_Float16)(a1 - (float)h1);
}

// --------------------------- fused LSTM step --------------------------------
// gates[B,4H] = [x_t | h_{t-1}] @ Wcat^T + bias, then cell, h -> hs[t+1].
// Block: 64 batch-rows x 16 H-cols x 4 gates (64 gate-rows).  Grid 256.
// K=2048, BK=64 windows, 32 iters.  Waves: wid = (mh | kh<<1):
//   mh = m-half (32 rows), kh = k-half of the window (32 k).
// A: direct global->VGPR 32x32x16 fragment loads, pipelined 2 iters ahead.
// B: 4 x 8KB LDS buffers, depth-3 prefetch, counted vmcnt, 1 barrier/iter.
// VMEM groups fenced with asm ""::: "memory" so issue order is pinned and
// the counted vmcnt values (guaranteed-younger counts) are sound.
__global__ __launch_bounds__(256) void k_step(const _Float16* __restrict__ Xh,
                                              const _Float16* __restrict__ Wc,
                                              const float* __restrict__ bias,
                                              _Float16* __restrict__ hs,
                                              float* __restrict__ cbuf,
                                              int t) {
  __shared__ char smem[65536];   // [0,32K) B bufs; epilogue: G@0, EX@32768
  const int tid = threadIdx.x;
  const int wid = tid >> 6;
  const int lane = tid & 63;
  const int mh = wid & 1;
  const int kh = wid >> 1;
  const int n_tile = blockIdx.x & 63;
  const int m_tile = blockIdx.x >> 6;
  const int n0 = n_tile * 16;
  const int m0 = m_tile * 64;

  const _Float16* Xt = Xh + (size_t)t * BH;
  const _Float16* Hp = hs + (size_t)t * BH;

  f32x16 acc0 = {0.f};   // gate-rows 0..31 (gates i,f)
  f32x16 acc1 = {0.f};   // gate-rows 32..63 (gates g,o)

  // ---- B staging: 8KB window tile [64 gr][8 chunks], slot=(chunk+row)&7 ---
  int offB[2];
  #pragma unroll
  for (int q = 0; q < 2; ++q) {
    int s = q * 256 + tid;
    int r = s >> 3, c = s & 7;
    int kc = (c - r) & 7;                 // slot c of row r holds data chunk kc
    offB[q] = ((r >> 4) * 1024 + n0 + (r & 15)) * 2048 + kc * 8;
  }
  auto stage = [&](int buf, int k0) {
    char* base = smem + buf * 8192;
    #pragma unroll
    for (int q = 0; q < 2; ++q)
      g2l16(base + (q * 4 + wid) * 1024, Wc + offB[q] + k0);
  };

  // ---- A fragment loads (32x32x16 layout: row=lane&31, k=(lane>>5)*8) -----
  const int arow = m0 + mh * 32 + (lane & 31);
  const int acol = kh * 32 + (lane >> 5) * 8;    // within 64-wide window
  auto loadA = [&](int i, half8& a0, half8& a1) {
    int k = i * 64 + acol;
    const _Float16* src = (i < 16) ? (Xt + (size_t)arow * 1024 + k)
                                   : (Hp + (size_t)arow * 1024 + (k - 1024));
    a0 = *(const half8*)(src);        // window k16-chunk 0/1 (by lane half)
    a1 = *(const half8*)(src + 16);   // window k16-chunk 2/3
  };

  // ---- B fragment read: frag f (gr f*32+lane&31), window chunk j in {0,1} -
  auto rdB = [&](const char* bb, int f, int j) -> half8 {
    int r = f * 32 + (lane & 31);
    int cd = 4 * kh + 2 * j + (lane >> 5);       // data 16B-chunk index 0..7
    return *(const half8*)(bb + r * 128 + (((cd + r) & 7) * 16));
  };

  half8 a00, a01, a10, a11;
  loadA(0, a00, a01);
  loadA(1, a10, a11);
  asm volatile("" ::: "memory");
  stage(0, 0);
  asm volatile("" ::: "memory");
  stage(1, 64);
  asm volatile("" ::: "memory");
  stage(2, 128);
  asm volatile("" ::: "memory");

  #pragma unroll
  for (int i = 0; i < 32; ++i) {
    // guaranteed-younger-than-stage(i) op counts (order pinned by fences):
    const int vn = (i == 0) ? 4 : (i == 1) ? 6 : (i <= 29) ? 8
                 : (i == 30) ? 6 : 2;
    if (vn == 4)      asm volatile("s_waitcnt vmcnt(4)" ::: "memory");
    else if (vn == 6) asm volatile("s_waitcnt vmcnt(6)" ::: "memory");
    else if (vn == 8) asm volatile("s_waitcnt vmcnt(8)" ::: "memory");
    else              asm volatile("s_waitcnt vmcnt(2)" ::: "memory");
    __builtin_amdgcn_s_barrier();

    const char* bb = smem + (i & 3) * 8192;
    half8 b00 = rdB(bb, 0, 0);
    half8 b10 = rdB(bb, 1, 0);
    half8 b01 = rdB(bb, 0, 1);
    half8 b11 = rdB(bb, 1, 1);
    acc0 = __builtin_amdgcn_mfma_f32_32x32x16_f16(a00, b00, acc0, 0, 0, 0);
    acc1 = __builtin_amdgcn_mfma_f32_32x32x16_f16(a00, b10, acc1, 0, 0, 0);
    acc0 = __builtin_amdgcn_mfma_f32_32x32x16_f16(a01, b01, acc0, 0, 0, 0);
    acc1 = __builtin_amdgcn_mfma_f32_32x32x16_f16(a01, b11, acc1, 0, 0, 0);
    a00 = a10; a01 = a11;

    asm volatile("" ::: "memory");
    if (i + 2 < 32) loadA(i + 2, a10, a11);
    asm volatile("" ::: "memory");
    if (i + 3 < 32) stage((i + 3) & 3, (i + 3) * 64);
    asm volatile("" ::: "memory");
  }

  asm volatile("s_waitcnt vmcnt(0)" ::: "memory");
  __syncthreads();

  // ---- epilogue: k-half reduce + gate regroup through LDS ------------------
  // C layout (32x32): col = lane&31 (B row), row = (e&3)+8*(e>>2)+4*(lane>>5).
  float* EX = (float*)(smem + 32768);       // [2 mh][64 gr][pad 33] f32
  if (kh == 1) {
    float* base = EX + mh * 2112;
    #pragma unroll
    for (int f = 0; f < 2; ++f) {
      const f32x16 a = f ? acc1 : acc0;
      int gr = f * 32 + (lane & 31);
      #pragma unroll
      for (int e = 0; e < 16; ++e) {
        int mr = (e & 3) + 8 * (e >> 2) + 4 * (lane >> 5);
        base[gr * 33 + mr] = a[e];
      }
    }
  }
  __syncthreads();
  float* G = (float*)smem;                  // [64 m][pad 66] gate-row cols
  if (kh == 0) {
    const float* base = EX + mh * 2112;
    #pragma unroll
    for (int f = 0; f < 2; ++f) {
      const f32x16 a = f ? acc1 : acc0;
      int gr = f * 32 + (lane & 31);
      #pragma unroll
      for (int e = 0; e < 16; ++e) {
        int mr = (e & 3) + 8 * (e >> 2) + 4 * (lane >> 5);
        G[(mh * 32 + mr) * 66 + gr] = a[e] + base[gr * 33 + mr];
      }
    }
  }
  __syncthreads();

  // ---- cell update: thread = (m-seg, nl) ----------------------------------
  {
    int nl = tid & 15;
    int mseg = tid >> 4;
    int n = n0 + nl;
    float bi = bias[n], bf2 = bias[1024 + n];
    float bg = bias[2048 + n], bo = bias[3072 + n];
    _Float16* hnext = hs + (size_t)(t + 1) * BH;
    #pragma unroll
    for (int rr = 0; rr < 4; ++rr) {
      int m = mseg * 4 + rr;
      const float* g = G + m * 66;
      float gi = sigmoidf_(g[nl] + bi);
      float gf = sigmoidf_(g[16 + nl] + bf2);
      float gg = tanhf_(g[32 + nl] + bg);
      float go = sigmoidf_(g[48 + nl] + bo);
      size_t idx = (size_t)(m0 + m) * 1024 + n;
      float c = gf * cbuf[idx] + gi * gg;
      cbuf[idx] = c;
      hnext[idx] = (_Float16)(go * tanhf_(c));
    }
  }
}

// --------------------------- attention mix (MFMA) ---------------------------
// att[x, n] = sum_y (Ah+Ar)[x,y] * hs[y+1, n].
__global__ __launch_bounds__(256) void k_attn(const _Float16* __restrict__ Ah,
                                              const _Float16* __restrict__ Ar,
                                              const _Float16* __restrict__ hs,
                                              _Float16* __restrict__ att) {
  __shared__ char smem[131072];
  const int tid = threadIdx.x;
  const int wave = tid >> 6;
  const int lane = tid & 63;
  const int n0 = blockIdx.x * 256;

  #pragma unroll
  for (int q = 0; q < 16; ++q) {
    int s = q * 256 + tid;
    char* dst = smem + (q * 4 + wave) * 1024;
    if (q < 8) {
      int r = s >> 4;
      int cl = (s & 15) ^ (r & 15);
      g2l16(dst, Ah + r * 128 + cl * 8);
    } else {
      int s2 = s - 2048;
      int r = s2 >> 4;
      int cl = (s2 & 15) ^ (r & 15);
      g2l16(dst, Ar + r * 128 + cl * 8);
    }
  }
  #pragma unroll
  for (int ch = 0; ch < 4; ++ch) {
    char* base = smem + 65536 + ch * 16384;
    #pragma unroll
    for (int q = 0; q < 4; ++q) {
      int s = q * 256 + tid;
      int y = s >> 5, cp = s & 31;
      int cl = cp ^ (((y >> 3) & 3) << 1);
      g2l16(base + (q * 4 + wave) * 1024,
            hs + (size_t)(1 + ch * 32 + y) * BH + n0 + cl * 8);
    }
  }

  f32x4 acc[8][4];
  #pragma unroll
  for (int m = 0; m < 8; ++m)
    #pragma unroll
    for (int nf = 0; nf < 4; ++nf) acc[m][nf] = (f32x4){0.f, 0.f, 0.f, 0.f};

  const int yg = lane >> 4;

  #pragma unroll
  for (int ch = 0; ch < 4; ++ch) {
    if (ch == 0)      asm volatile("s_waitcnt vmcnt(12)" ::: "memory");
    else if (ch == 1) asm volatile("s_waitcnt vmcnt(8)"  ::: "memory");
    else if (ch == 2) asm volatile("s_waitcnt vmcnt(4)"  ::: "memory");
    else              asm volatile("s_waitcnt vmcnt(0)"  ::: "memory");
    __builtin_amdgcn_s_barrier();

    const char* cb = smem + 65536 + ch * 16384;
    half8 b[4];
    #pragma unroll
    for (int nf = 0; nf < 4; ++nf) {
      int n = wave * 64 + nf * 16 + (lane & 15);
      const char* col = cb + (((n >> 3) ^ (yg << 1)) * 16) + (n & 7) * 2;
      #pragma unroll
      for (int j = 0; j < 8; ++j)
        b[nf][j] = *(const _Float16*)(col + (yg * 8 + j) * 512);
    }
    #pragma unroll
    for (int m = 0; m < 8; ++m) {
      int x = m * 16 + (lane & 15);
      int sw = ((ch * 4 + yg) ^ (x & 15)) * 16;
      half8 ah = *(const half8*)(smem + x * 256 + sw);
      half8 ar = *(const half8*)(smem + 32768 + x * 256 + sw);
      #pragma unroll
      for (int nf = 0; nf < 4; ++nf) {
        acc[m][nf] = __builtin_amdgcn_mfma_f32_16x16x32_f16(ah, b[nf], acc[m][nf], 0, 0, 0);
        acc[m][nf] = __builtin_amdgcn_mfma_f32_16x16x32_f16(ar, b[nf], acc[m][nf], 0, 0, 0);
      }
    }
  }

  #pragma unroll
  for (int m = 0; m < 8; ++m) {
    int x0 = m * 16 + (lane >> 4) * 4;
    #pragma unroll
    for (int nf = 0; nf < 4; ++nf) {
      int n = n0 + wave * 64 + nf * 16 + (lane & 15);
      #pragma unroll
      for (int r = 0; r < 4; ++r)
        att[(size_t)(x0 + r) * BH + n] = (_Float16)acc[m][nf][r];
    }
  }
}

// --------------------------- final linear -----------------------------------
// out[32768,1024] = att @ linW^T + linb.  128x128 tile, BK=64, dbuf LDS.
// bid remap: XCD = bid&7 owns m-tiles [32*xcd, 32*xcd+32); n = (bid>>3)&7.
__global__ __launch_bounds__(256) void k_final(const _Float16* __restrict__ att,
                                               const _Float16* __restrict__ Wl,
                                               const float* __restrict__ bvec,
                                               float* __restrict__ out) {
  __shared__ char smem[65536];
  const int tid = threadIdx.x, wave = tid >> 6, lane = tid & 63;
  const int j = blockIdx.x >> 3;
  const int m0 = (((blockIdx.x & 7) << 5) | (j >> 3)) * 128;
  const int n0 = (j & 7) * 128;
  const int mh = (wave & 1) * 64, nh = (wave >> 1) * 64;

  f32x4 acc[4][4];
  #pragma unroll
  for (int i = 0; i < 4; ++i)
    #pragma unroll
    for (int jj = 0; jj < 4; ++jj) acc[i][jj] = (f32x4){0.f, 0.f, 0.f, 0.f};

  auto stage = [&](int p, int k0) {
    char* base = smem + p * 32768;
    #pragma unroll
    for (int q = 0; q < 8; ++q) {
      int grp = q * 4 + wave;
      char* dst = base + grp * 1024;
      int s = grp * 64 + lane;
      if (s < 1024) {
        int r = s >> 3, c = s & 7;
        int kc = c ^ (r & 7);
        g2l16(dst, att + (size_t)(m0 + r) * 1024 + k0 + kc * 8);
      } else {
        int sb = s - 1024;
        int r = sb >> 3, c = sb & 7;
        int kc = c ^ (r & 7);
        g2l16(dst, Wl + (size_t)(n0 + r) * 1024 + k0 + kc * 8);
      }
    }
  };

  stage(0, 0);
  for (int iter = 0; iter < 16; ++iter) {
    int p = iter & 1;
    __syncthreads();
    if (iter + 1 < 16) stage(1 - p, (iter + 1) * 64);
    const char* At = smem + p * 32768;
    const char* Bt = At + 16384;
    #pragma unroll
    for (int k32 = 0; k32 < 2; ++k32) {
      int kc = k32 * 4 + (lane >> 4);
      half8 a[4], b[4];
      #pragma unroll
      for (int i = 0; i < 4; ++i) {
        int ra = mh + i * 16 + (lane & 15);
        a[i] = *(const half8*)(At + ra * 128 + ((kc ^ (ra & 7)) * 16));
        int rb = nh + i * 16 + (lane & 15);
        b[i] = *(const half8*)(Bt + rb * 128 + ((kc ^ (rb & 7)) * 16));
      }
      #pragma unroll
      for (int i = 0; i < 4; ++i)
        #pragma unroll
        for (int jj = 0; jj < 4; ++jj)
          acc[i][jj] = __builtin_amdgcn_mfma_f32_16x16x32_f16(a[i], b[jj], acc[i][jj], 0, 0, 0);
    }
  }

  #pragma unroll
  for (int i = 0; i < 4; ++i) {
    int m = m0 + mh + i * 16 + (lane >> 4) * 4;
    #pragma unroll
    for (int jj = 0; jj < 4; ++jj) {
      int n = n0 + nh + jj * 16 + (lane & 15);
      float bv = bvec[n];
      #pragma unroll
      for (int r = 0; r < 4; ++r)
        out[(size_t)(m + r) * 1024 + n] = acc[i][jj][r] + bv;
    }
  }
}

// --------------------------- launch -----------------------------------------
extern "C" void kernel_launch(void* const* d_in, const int* in_sizes, int n_in,
                              void* d_out, int out_size, void* d_ws, size_t ws_size,
                              hipStream_t stream) {
  const float* X     = (const float*)d_in[0];
  const float* h0    = (const float*)d_in[1];
  const float* c0    = (const float*)d_in[2];
  const float* Wih   = (const float*)d_in[3];
  const float* Whh   = (const float*)d_in[4];
  const float* bih   = (const float*)d_in[5];
  const float* bhh   = (const float*)d_in[6];
  const float* attnW = (const float*)d_in[7];
  const float* linW  = (const float*)d_in[8];
  const float* linb  = (const float*)d_in[9];
  float* out = (float*)d_out;
  char* ws = (char*)d_ws;

  // workspace layout (bytes), ~212 MB total
  _Float16* Xh  = (_Float16*)(ws + 0);           // 67,108,864
  _Float16* Wc  = (_Float16*)(ws + 67108864);    // 16,777,216
  _Float16* Wl  = (_Float16*)(ws + 83886080);    //  2,097,152
  _Float16* hs  = (_Float16*)(ws + 85983232);    // 129 slots * 524,288
  _Float16* att = (_Float16*)(ws + 153616384);   // 67,108,864
  float* cbuf   = (float*)(ws + 220725248);      //  1,048,576
  float* bias   = (float*)(ws + 221773824);      //     16,384
  _Float16* Ahm = (_Float16*)(ws + 221790208);   //     32,768
  _Float16* Arm = (_Float16*)(ws + 221822976);   //     32,768

  k_cvt<<<16384, 256, 0, stream>>>(X, Xh);
  k_wcat<<<4096, 256, 0, stream>>>(Wih, Whh, Wc);
  k_cvt<<<512, 256, 0, stream>>>(linW, Wl);
  k_init<<<1024, 256, 0, stream>>>(h0, c0, bih, bhh, hs, cbuf, bias);
  k_softmax<<<128, 64, 0, stream>>>(attnW, Ahm, Arm);

  for (int t = 0; t < S_; ++t)
    k_step<<<256, 256, 0, stream>>>(Xh, Wc, bias, hs, cbuf, t);

  k_attn<<<1024, 256, 0, stream>>>(Ahm, Arm, hs, att);
  k_final<<<2048, 256, 0, stream>>>(att, Wl, linb, out);
}

// Round 5
// 1635.947 us; speedup vs baseline: 1.6892x; 1.6892x over previous
//
#include <hip/hip_runtime.h>

// ---------------------------------------------------------------------------
// LSTM autoencoder w/ attention, MI355X fp16-MFMA implementation.
// S=128, B=256, IN=H=OUT=1024.  All GEMMs plain fp16 inputs, fp32 accumulate.
// R6: k_step reverted to the R1 pipeline (proven 1729us run) but widened to
//     512 threads: waves 0-3 compute the x-half of K, waves 4-7 the h-half,
//     each group running R1's exact 16-iter 4-buffer counted-vmcnt loop in
//     its own 64KB LDS region (128KB total, 1 block/CU, 2 waves/SIMD).
//     fp32 k-half partials merge via a 34KB LDS exchange (R5-verified
//     pattern), then the fused cell update.  Latency hiding doubles while
//     the per-iter instruction mix stays identical.
// ---------------------------------------------------------------------------

typedef _Float16 half8 __attribute__((ext_vector_type(8)));
typedef float f32x4 __attribute__((ext_vector_type(4)));

#define S_  128
#define B_  256
#define HDIM 1024
#define BH  262144          // B*H

// async global -> LDS, 16B per lane, wave-uniform LDS base
__device__ __forceinline__ void g2l16(void* lds_base, const void* g) {
  __builtin_amdgcn_global_load_lds(
      (const __attribute__((address_space(1))) void*)g,
      (__attribute__((address_space(3))) void*)lds_base, 16, 0, 0);
}

__device__ __forceinline__ float sigmoidf_(float x) {
  return 1.f / (1.f + __expf(-x));
}
__device__ __forceinline__ float tanhf_(float x) {
  float e = __expf(-2.f * fabsf(x));
  float t = (1.f - e) / (1.f + e);
  return x < 0.f ? -t : t;
}

// --------------------------- converters ------------------------------------
__global__ __launch_bounds__(256) void k_cvt(const float* __restrict__ src,
                                             _Float16* __restrict__ dst) {
  size_t i = ((size_t)blockIdx.x * 256 + threadIdx.x) * 8;
  float4 u = *(const float4*)(src + i);
  float4 v = *(const float4*)(src + i + 4);
  half8 h;
  h[0] = u.x; h[1] = u.y; h[2] = u.z; h[3] = u.w;
  h[4] = v.x; h[5] = v.y; h[6] = v.z; h[7] = v.w;
  *(half8*)(dst + i) = h;
}

// Wcat[r][k] = k<1024 ? W_ih[r][k] : W_hh[r][k-1024]   (fp16, [4096][2048])
__global__ __launch_bounds__(256) void k_wcat(const float* __restrict__ Wih,
                                              const float* __restrict__ Whh,
                                              _Float16* __restrict__ Wc) {
  size_t i = ((size_t)blockIdx.x * 256 + threadIdx.x) * 8;
  int r = (int)(i >> 11), k = (int)(i & 2047);
  const float* src = (k < 1024) ? (Wih + (size_t)r * 1024 + k)
                                : (Whh + (size_t)r * 1024 + (k - 1024));
  float4 u = *(const float4*)(src);
  float4 v = *(const float4*)(src + 4);
  half8 h;
  h[0] = u.x; h[1] = u.y; h[2] = u.z; h[3] = u.w;
  h[4] = v.x; h[5] = v.y; h[6] = v.z; h[7] = v.w;
  *(half8*)(Wc + i) = h;
}

// cbuf = c0 ; hs[0] = fp16(h0) ; bias = b_ih + b_hh
__global__ __launch_bounds__(256) void k_init(const float* __restrict__ h0,
                                              const float* __restrict__ c0,
                                              const float* __restrict__ bih,
                                              const float* __restrict__ bhh,
                                              _Float16* __restrict__ hs0,
                                              float* __restrict__ cbuf,
                                              float* __restrict__ bias) {
  int i = blockIdx.x * 256 + threadIdx.x;   // 262144 total
  cbuf[i] = c0[i];
  hs0[i] = (_Float16)h0[i];
  if (i < 4096) bias[i] = bih[i] + bhh[i];
}

// row softmax of attnW [128][128] -> fp16 Ah + fp16 residual Ar
__global__ __launch_bounds__(64) void k_softmax(const float* __restrict__ W,
                                                _Float16* __restrict__ Ah,
                                                _Float16* __restrict__ Ar) {
  int r = blockIdx.x, lane = threadIdx.x;
  float v0 = W[r * 128 + lane], v1 = W[r * 128 + 64 + lane];
  float m = fmaxf(v0, v1);
  for (int off = 32; off; off >>= 1) m = fmaxf(m, __shfl_xor(m, off));
  float e0 = __expf(v0 - m), e1 = __expf(v1 - m);
  float s = e0 + e1;
  for (int off = 32; off; off >>= 1) s += __shfl_xor(s, off);
  float inv = 1.f / s;
  float a0 = e0 * inv, a1 = e1 * inv;
  _Float16 h0 = (_Float16)a0, h1 = (_Float16)a1;
  Ah[r * 128 + lane] = h0;
  Ah[r * 128 + 64 + lane] = h1;
  Ar[r * 128 + lane] = (_Float16)(a0 - (float)h0);
  Ar[r * 128 + 64 + lane] = (_Float16)(a1 - (float)h1);
}

// --------------------------- fused LSTM step --------------------------------
// gates[B,4H] = [x_t | h_{t-1}] @ Wcat^T + bias, then cell, h -> hs[t+1].
// Block: 64 batch-rows x 16 H-cols x 4 gates.  Grid 256, 512 threads.
// Wave-group kg = wid>>2 handles K-half kg (x or h); within a group the
// loop is R1's: BK=64, 4x16KB LDS buffers, depth-2 prefetch, counted vmcnt,
// one barrier/iter.  Groups run in lockstep (shared s_barrier), partials
// merge in fp32 through LDS, all 512 threads do the cell update.
__global__ __launch_bounds__(512) void k_step(const _Float16* __restrict__ Xh,
                                              const _Float16* __restrict__ Wc,
                                              const float* __restrict__ bias,
                                              _Float16* __restrict__ hs,
                                              float* __restrict__ cbuf,
                                              int t) {
  __shared__ char smem[131072];   // [0,64K) group0 bufs, [64K,128K) group1
  const int tid = threadIdx.x;
  const int wid = tid >> 6;
  const int lane = tid & 63;
  const int kg = wid >> 2;          // 0: x-half of K, 1: h-half
  const int wv = wid & 3;           // wave within group = m-quarter
  const int tg = tid & 255;         // thread id within group
  const int n_tile = blockIdx.x & 63;
  const int m_tile = blockIdx.x >> 6;
  const int n0 = n_tile * 16;
  const int m0 = m_tile * 64;

  const _Float16* Asrc = (kg == 0) ? (Xh + (size_t)t * BH)
                                   : (hs + (size_t)t * BH);
  const int kbase = kg * 1024;

  f32x4 acc[4];
  #pragma unroll
  for (int g = 0; g < 4; ++g) acc[g] = (f32x4){0.f, 0.f, 0.f, 0.f};

  // per-thread staging source offsets.  Buffer: A 64x64 (8KB) + B 64x64 (8KB)
  // LDS row = 128B = 8 chunks, XOR swizzle c ^ (r & 7).
  int offA[2], offB[2];
  #pragma unroll
  for (int q = 0; q < 4; ++q) {
    int s = q * 256 + tg;
    if (q < 2) {                       // A tile: x/h rows
      int r = s >> 3, c = s & 7;
      int kc = c ^ (r & 7);
      offA[q] = (m0 + r) * 1024 + kc * 8;
    } else {                           // B tile: 4 gate strips x 16 rows
      int sb = s - 512;
      int r = sb >> 3, c = sb & 7;
      int kc = c ^ (r & 7);
      int row = (r >> 4) * 1024 + n0 + (r & 15);
      offB[q - 2] = row * 2048 + kbase + kc * 8;
    }
  }

  char* gbase = smem + kg * 65536;
  auto stage = [&](int buf, int k0) {
    char* base = gbase + buf * 16384;
    #pragma unroll
    for (int q = 0; q < 4; ++q) {
      char* dst = base + (q * 4 + wv) * 1024;       // wave-uniform
      if (q < 2) g2l16(dst, Asrc + offA[q] + k0);
      else       g2l16(dst, Wc + offB[q - 2] + k0);
    }
  };

  // per-lane LDS read offsets (constant across iters)
  const int ra = wv * 16 + (lane & 15);
  const int kcl = lane >> 4;                        // 0..3
  const int aoff0 = ra * 128 + ((kcl ^ (ra & 7)) * 16);
  const int aoff1 = ra * 128 + (((kcl + 4) ^ (ra & 7)) * 16);
  int boff0[4], boff1[4];
  #pragma unroll
  for (int g = 0; g < 4; ++g) {
    int rb = g * 16 + (lane & 15);
    boff0[g] = 8192 + rb * 128 + ((kcl ^ (rb & 7)) * 16);
    boff1[g] = 8192 + rb * 128 + (((kcl + 4) ^ (rb & 7)) * 16);
  }

  stage(0, 0);
  stage(1, 64);

  #pragma unroll
  for (int iter = 0; iter < 16; ++iter) {
    if (iter < 14) stage((iter + 2) & 3, (iter + 2) * 64);
    // drain this buffer's 4 loads; keep up to 8 (2 buffers) in flight.
    if (iter < 14)       asm volatile("s_waitcnt vmcnt(8)" ::: "memory");
    else if (iter == 14) asm volatile("s_waitcnt vmcnt(4)" ::: "memory");
    else                 asm volatile("s_waitcnt vmcnt(0)" ::: "memory");
    __builtin_amdgcn_s_barrier();                   // buffer ready (all waves)
    const char* At = gbase + (iter & 3) * 16384;
    half8 a0 = *(const half8*)(At + aoff0);
    half8 a1 = *(const half8*)(At + aoff1);
    #pragma unroll
    for (int g = 0; g < 4; ++g) {
      half8 b0 = *(const half8*)(At + boff0[g]);
      acc[g] = __builtin_amdgcn_mfma_f32_16x16x32_f16(a0, b0, acc[g], 0, 0, 0);
    }
    #pragma unroll
    for (int g = 0; g < 4; ++g) {
      half8 b1 = *(const half8*)(At + boff1[g]);
      acc[g] = __builtin_amdgcn_mfma_f32_16x16x32_f16(a1, b1, acc[g], 0, 0, 0);
    }
  }

  __syncthreads();                    // all waves done with buffers

  // ---- k-half partial exchange: EX[kg][64 m][66 pad] fp32 ------------------
  // C layout per 16x16 tile: col = lane&15, row = (lane>>4)*4 + r.
  {
    float* EXg = (float*)smem + kg * 4224;
    #pragma unroll
    for (int g = 0; g < 4; ++g) {
      int gc = g * 16 + (lane & 15);
      int mb = wv * 16 + (lane >> 4) * 4;
      #pragma unroll
      for (int r = 0; r < 4; ++r)
        EXg[(mb + r) * 66 + gc] = acc[g][r];
    }
  }
  __syncthreads();

  // ---- cell update: 512 threads, 2 m-rows each ----------------------------
  {
    int nl = tid & 15;
    int mseg = tid >> 4;              // 0..31
    int n = n0 + nl;
    float bi = bias[n], bf2 = bias[1024 + n];
    float bg = bias[2048 + n], bo = bias[3072 + n];
    const float* E0 = (float*)smem;
    const float* E1 = E0 + 4224;
    _Float16* hnext = hs + (size_t)(t + 1) * BH;
    #pragma unroll
    for (int rr = 0; rr < 2; ++rr) {
      int m = mseg * 2 + rr;
      const float* e0 = E0 + m * 66;
      const float* e1 = E1 + m * 66;
      float gi = sigmoidf_(e0[nl]      + e1[nl]      + bi);
      float gf = sigmoidf_(e0[16 + nl] + e1[16 + nl] + bf2);
      float gg = tanhf_   (e0[32 + nl] + e1[32 + nl] + bg);
      float go = sigmoidf_(e0[48 + nl] + e1[48 + nl] + bo);
      size_t idx = (size_t)(m0 + m) * 1024 + n;
      float c = gf * cbuf[idx] + gi * gg;
      cbuf[idx] = c;
      hnext[idx] = (_Float16)(go * tanhf_(c));
    }
  }
}

// --------------------------- attention mix (MFMA) ---------------------------
// att[x, n] = sum_y (Ah+Ar)[x,y] * hs[y+1, n].
__global__ __launch_bounds__(256) void k_attn(const _Float16* __restrict__ Ah,
                                              const _Float16* __restrict__ Ar,
                                              const _Float16* __restrict__ hs,
                                              _Float16* __restrict__ att) {
  __shared__ char smem[131072];
  const int tid = threadIdx.x;
  const int wave = tid >> 6;
  const int lane = tid & 63;
  const int n0 = blockIdx.x * 256;

  #pragma unroll
  for (int q = 0; q < 16; ++q) {
    int s = q * 256 + tid;
    char* dst = smem + (q * 4 + wave) * 1024;
    if (q < 8) {
      int r = s >> 4;
      int cl = (s & 15) ^ (r & 15);
      g2l16(dst, Ah + r * 128 + cl * 8);
    } else {
      int s2 = s - 2048;
      int r = s2 >> 4;
      int cl = (s2 & 15) ^ (r & 15);
      g2l16(dst, Ar + r * 128 + cl * 8);
    }
  }
  #pragma unroll
  for (int ch = 0; ch < 4; ++ch) {
    char* base = smem + 65536 + ch * 16384;
    #pragma unroll
    for (int q = 0; q < 4; ++q) {
      int s = q * 256 + tid;
      int y = s >> 5, cp = s & 31;
      int cl = cp ^ (((y >> 3) & 3) << 1);
      g2l16(base + (q * 4 + wave) * 1024,
            hs + (size_t)(1 + ch * 32 + y) * BH + n0 + cl * 8);
    }
  }

  f32x4 acc[8][4];
  #pragma unroll
  for (int m = 0; m < 8; ++m)
    #pragma unroll
    for (int nf = 0; nf < 4; ++nf) acc[m][nf] = (f32x4){0.f, 0.f, 0.f, 0.f};

  const int yg = lane >> 4;

  #pragma unroll
  for (int ch = 0; ch < 4; ++ch) {
    if (ch == 0)      asm volatile("s_waitcnt vmcnt(12)" ::: "memory");
    else if (ch == 1) asm volatile("s_waitcnt vmcnt(8)"  ::: "memory");
    else if (ch == 2) asm volatile("s_waitcnt vmcnt(4)"  ::: "memory");
    else              asm volatile("s_waitcnt vmcnt(0)"  ::: "memory");
    __builtin_amdgcn_s_barrier();

    const char* cb = smem + 65536 + ch * 16384;
    half8 b[4];
    #pragma unroll
    for (int nf = 0; nf < 4; ++nf) {
      int n = wave * 64 + nf * 16 + (lane & 15);
      const char* col = cb + (((n >> 3) ^ (yg << 1)) * 16) + (n & 7) * 2;
      #pragma unroll
      for (int j = 0; j < 8; ++j)
        b[nf][j] = *(const _Float16*)(col + (yg * 8 + j) * 512);
    }
    #pragma unroll
    for (int m = 0; m < 8; ++m) {
      int x = m * 16 + (lane & 15);
      int sw = ((ch * 4 + yg) ^ (x & 15)) * 16;
      half8 ah = *(const half8*)(smem + x * 256 + sw);
      half8 ar = *(const half8*)(smem + 32768 + x * 256 + sw);
      #pragma unroll
      for (int nf = 0; nf < 4; ++nf) {
        acc[m][nf] = __builtin_amdgcn_mfma_f32_16x16x32_f16(ah, b[nf], acc[m][nf], 0, 0, 0);
        acc[m][nf] = __builtin_amdgcn_mfma_f32_16x16x32_f16(ar, b[nf], acc[m][nf], 0, 0, 0);
      }
    }
  }

  #pragma unroll
  for (int m = 0; m < 8; ++m) {
    int x0 = m * 16 + (lane >> 4) * 4;
    #pragma unroll
    for (int nf = 0; nf < 4; ++nf) {
      int n = n0 + wave * 64 + nf * 16 + (lane & 15);
      #pragma unroll
      for (int r = 0; r < 4; ++r)
        att[(size_t)(x0 + r) * BH + n] = (_Float16)acc[m][nf][r];
    }
  }
}

// --------------------------- final linear -----------------------------------
// out[32768,1024] = att @ linW^T + linb.  128x128 tile, BK=64, dbuf LDS.
// bid remap: XCD = bid&7 owns m-tiles [32*xcd, 32*xcd+32); n = (bid>>3)&7.
__global__ __launch_bounds__(256) void k_final(const _Float16* __restrict__ att,
                                               const _Float16* __restrict__ Wl,
                                               const float* __restrict__ bvec,
                                               float* __restrict__ out) {
  __shared__ char smem[65536];
  const int tid = threadIdx.x, wave = tid >> 6, lane = tid & 63;
  const int j = blockIdx.x >> 3;
  const int m0 = (((blockIdx.x & 7) << 5) | (j >> 3)) * 128;
  const int n0 = (j & 7) * 128;
  const int mh = (wave & 1) * 64, nh = (wave >> 1) * 64;

  f32x4 acc[4][4];
  #pragma unroll
  for (int i = 0; i < 4; ++i)
    #pragma unroll
    for (int jj = 0; jj < 4; ++jj) acc[i][jj] = (f32x4){0.f, 0.f, 0.f, 0.f};

  auto stage = [&](int p, int k0) {
    char* base = smem + p * 32768;
    #pragma unroll
    for (int q = 0; q < 8; ++q) {
      int grp = q * 4 + wave;
      char* dst = base + grp * 1024;
      int s = grp * 64 + lane;
      if (s < 1024) {
        int r = s >> 3, c = s & 7;
        int kc = c ^ (r & 7);
        g2l16(dst, att + (size_t)(m0 + r) * 1024 + k0 + kc * 8);
      } else {
        int sb = s - 1024;
        int r = sb >> 3, c = sb & 7;
        int kc = c ^ (r & 7);
        g2l16(dst, Wl + (size_t)(n0 + r) * 1024 + k0 + kc * 8);
      }
    }
  };

  stage(0, 0);
  for (int iter = 0; iter < 16; ++iter) {
    int p = iter & 1;
    __syncthreads();
    if (iter + 1 < 16) stage(1 - p, (iter + 1) * 64);
    const char* At = smem + p * 32768;
    const char* Bt = At + 16384;
    #pragma unroll
    for (int k32 = 0; k32 < 2; ++k32) {
      int kc = k32 * 4 + (lane >> 4);
      half8 a[4], b[4];
      #pragma unroll
      for (int i = 0; i < 4; ++i) {
        int ra = mh + i * 16 + (lane & 15);
        a[i] = *(const half8*)(At + ra * 128 + ((kc ^ (ra & 7)) * 16));
        int rb = nh + i * 16 + (lane & 15);
        b[i] = *(const half8*)(Bt + rb * 128 + ((kc ^ (rb & 7)) * 16));
      }
      #pragma unroll
      for (int i = 0; i < 4; ++i)
        #pragma unroll
        for (int jj = 0; jj < 4; ++jj)
          acc[i][jj] = __builtin_amdgcn_mfma_f32_16x16x32_f16(a[i], b[jj], acc[i][jj], 0, 0, 0);
    }
  }

  #pragma unroll
  for (int i = 0; i < 4; ++i) {
    int m = m0 + mh + i * 16 + (lane >> 4) * 4;
    #pragma unroll
    for (int jj = 0; jj < 4; ++jj) {
      int n = n0 + nh + jj * 16 + (lane & 15);
      float bv = bvec[n];
      #pragma unroll
      for (int r = 0; r < 4; ++r)
        out[(size_t)(m + r) * 1024 + n] = acc[i][jj][r] + bv;
    }
  }
}

// --------------------------- launch -----------------------------------------
extern "C" void kernel_launch(void* const* d_in, const int* in_sizes, int n_in,
                              void* d_out, int out_size, void* d_ws, size_t ws_size,
                              hipStream_t stream) {
  const float* X     = (const float*)d_in[0];
  const float* h0    = (const float*)d_in[1];
  const float* c0    = (const float*)d_in[2];
  const float* Wih   = (const float*)d_in[3];
  const float* Whh   = (const float*)d_in[4];
  const float* bih   = (const float*)d_in[5];
  const float* bhh   = (const float*)d_in[6];
  const float* attnW = (const float*)d_in[7];
  const float* linW  = (const float*)d_in[8];
  const float* linb  = (const float*)d_in[9];
  float* out = (float*)d_out;
  char* ws = (char*)d_ws;

  // workspace layout (bytes), ~212 MB total
  _Float16* Xh  = (_Float16*)(ws + 0);           // 67,108,864
  _Float16* Wc  = (_Float16*)(ws + 67108864);    // 16,777,216
  _Float16* Wl  = (_Float16*)(ws + 83886080);    //  2,097,152
  _Float16* hs  = (_Float16*)(ws + 85983232);    // 129 slots * 524,288
  _Float16* att = (_Float16*)(ws + 153616384);   // 67,108,864
  float* cbuf   = (float*)(ws + 220725248);      //  1,048,576
  float* bias   = (float*)(ws + 221773824);      //     16,384
  _Float16* Ahm = (_Float16*)(ws + 221790208);   //     32,768
  _Float16* Arm = (_Float16*)(ws + 221822976);   //     32,768

  k_cvt<<<16384, 256, 0, stream>>>(X, Xh);
  k_wcat<<<4096, 256, 0, stream>>>(Wih, Whh, Wc);
  k_cvt<<<512, 256, 0, stream>>>(linW, Wl);
  k_init<<<1024, 256, 0, stream>>>(h0, c0, bih, bhh, hs, cbuf, bias);
  k_softmax<<<128, 64, 0, stream>>>(attnW, Ahm, Arm);

  for (int t = 0; t < S_; ++t)
    k_step<<<256, 512, 0, stream>>>(Xh, Wc, bias, hs, cbuf, t);

  k_attn<<<1024, 256, 0, stream>>>(Ahm, Arm, hs, att);
  k_final<<<2048, 256, 0, stream>>>(att, Wl, linb, out);
}